// Round 1
// baseline (461.295 us; speedup 1.0000x reference)
//
#include <hip/hip_runtime.h>
#include <cstdint>
#include <cstddef>

// SpikingHybridCoreFlow: 20-cycle spiking simulation.
// Strategy: exact fixed-point weights (4 x i8 planes, scale 2^-33),
// i8 MFMA integer GEMM (order-independent exact accumulation),
// fp64 membrane state. Spike trains replicated bit-exact in fp32.

#define N_DIM 2048
#define B_DIM 64
#define C_DIM 4
#define T_SIM 16
#define CYCLES 20

using i32x4 = __attribute__((ext_vector_type(4))) int;

// Workspace layout
//   WQ   : [C][4 planes][128 coltiles][32 ksteps][1024B blocks] = 67,108,864 B
//   MEMB : [C][B][N] double                                      =  4,194,304 B
//   SIG  : [2 ping-pong][4 channels][B*N] int8                   =  1,048,576 B
static constexpr size_t WQ_BYTES   = (size_t)C_DIM * 4 * 128 * 32 * 1024;
static constexpr size_t PLANE_STR  = (size_t)128 * 32 * 1024;   // 4,194,304
static constexpr size_t MEMB_OFF   = WQ_BYTES;
static constexpr size_t MEMB_BYTES = (size_t)C_DIM * B_DIM * N_DIM * 8;
static constexpr size_t SIG_OFF    = MEMB_OFF + MEMB_BYTES;
static constexpr size_t SIG_BYTES  = (size_t)2 * 4 * B_DIM * N_DIM;
static constexpr size_t CH_BYTES   = (size_t)B_DIM * N_DIM;     // one channel

// ---------------------------------------------------------------------------
// Quantize w (fp32) -> int32 fixed point (scale 2^33) -> 4 balanced i8 planes.
// Packed layout: block(c,p,ct,ks) of 1024B; byte index = lane*16 + j where
//   n = ct*16 + (lane&15), a = ks*64 + ((lane>>4)<<4) + j
// matching the MFMA i8 16x16x64 B-fragment (lane reads 16 contiguous bytes).
// ---------------------------------------------------------------------------
__global__ __launch_bounds__(64) void pack_w(const float* __restrict__ w,
                                             signed char* __restrict__ wq) {
    int blk = blockIdx.x;              // c*32*128 + ks*128 + ct
    int ct  = blk & 127;
    int ks  = (blk >> 7) & 31;
    int c   = blk >> 12;
    int l   = threadIdx.x;             // 0..63
    int n     = ct * 16 + (l & 15);
    int abase = ks * 64 + ((l >> 4) << 4);
    const float* wc = w + (size_t)c * N_DIM * N_DIM;
    size_t blk_base = ((((size_t)c * 4) * 128 + ct) * 32 + ks) * 1024 + (size_t)l * 16;

    for (int j4 = 0; j4 < 4; ++j4) {
        uint32_t dw0 = 0, dw1 = 0, dw2 = 0, dw3 = 0;
        for (int i = 0; i < 4; ++i) {
            int a = abase + j4 * 4 + i;
            float wv = wc[(size_t)a * N_DIM + n];
            long long vi = llrint((double)wv * 8589934592.0);  // * 2^33
            int v  = (int)vi;
            int b0 = (int)(signed char)(v & 255); v = (v - b0) >> 8;
            int b1 = (int)(signed char)(v & 255); v = (v - b1) >> 8;
            int b2 = (int)(signed char)(v & 255); v = (v - b2) >> 8;
            int b3 = v;                                        // fits in i8 by range
            dw0 |= (uint32_t)(uint8_t)b0 << (8 * i);
            dw1 |= (uint32_t)(uint8_t)b1 << (8 * i);
            dw2 |= (uint32_t)(uint8_t)b2 << (8 * i);
            dw3 |= (uint32_t)(uint8_t)b3 << (8 * i);
        }
        *(uint32_t*)(wq + blk_base + 0 * PLANE_STR + j4 * 4) = dw0;
        *(uint32_t*)(wq + blk_base + 1 * PLANE_STR + j4 * 4) = dw1;
        *(uint32_t*)(wq + blk_base + 2 * PLANE_STR + j4 * 4) = dw2;
        *(uint32_t*)(wq + blk_base + 3 * PLANE_STR + j4 * 4) = dw3;
    }
}

// ---------------------------------------------------------------------------
// Bit-exact replication of _uniform_spikes (all ops IEEE fp32, like XLA):
// rintf == jnp.round (half-even), fmodf == lax.rem (exact for positives).
// ---------------------------------------------------------------------------
__device__ __forceinline__ int in_spike(float xv, int cycle) {
    if (cycle >= T_SIM) return 0;
    float n_spk = rintf(xv * 16.0f);
    if (n_spk == 16.0f) return 1;
    if (n_spk == 0.0f)  return 0;
    float spacing = 16.0f / n_spk;
    float cf = (float)cycle;
    float q = floorf(cf / spacing);
    float r = fmodf(cf, spacing);
    return (q < n_spk && floorf(r) == 0.0f) ? 1 : 0;
}

__global__ __launch_bounds__(256) void gen_in(const float* __restrict__ x,
                                              signed char* __restrict__ sig, int t) {
    int gtid = blockIdx.x * 256 + threadIdx.x;    // 0..32767
    int e = gtid << 2;
    const float4 xv = *(const float4*)(x + e);
    uint32_t s = (uint32_t)in_spike(xv.x, t)
               | ((uint32_t)in_spike(xv.y, t) << 8)
               | ((uint32_t)in_spike(xv.z, t) << 16)
               | ((uint32_t)in_spike(xv.w, t) << 24);
    *(uint32_t*)(sig + (size_t)(t & 1) * 4 * CH_BYTES + e) = s;
}

// ---------------------------------------------------------------------------
// One simulation cycle. Grid: 512 WGs = 4 cores x 128 col-tiles(16), 256 thr.
// Wave w computes D rows [w*16, w*16+16) x 16 cols via 4-plane i8 MFMA.
// ---------------------------------------------------------------------------
__global__ __launch_bounds__(256, 2) void cycle_k(
        const signed char* __restrict__ wq, const float* __restrict__ x,
        const float* __restrict__ biases, const float* __restrict__ thresholds,
        double* __restrict__ memb, signed char* __restrict__ sig,
        float* __restrict__ out, int t)
{
    const int wg = blockIdx.x;
    const int c  = wg >> 7;
    const int ct = wg & 127;
    const int tid = threadIdx.x;
    const int w   = tid >> 6;
    const int l   = tid & 63;
    const int n0  = ct << 4;
    const int n   = n0 + (l & 15);

    // A operand: signals channel c, ping slot t&1.
    const signed char* A = sig + (size_t)((t & 1) * 4 + c) * CH_BYTES;
    const int arow = w * 16 + (l & 15);
    const signed char* aptr = A + (size_t)arow * N_DIM + ((l >> 4) << 4);
    // B operand: packed planes.
    const signed char* bbase = wq + (((size_t)c * 4 * 128 + ct) * 32) * 1024 + (size_t)l * 16;

    i32x4 acc0 = {0, 0, 0, 0}, acc1 = {0, 0, 0, 0};
    i32x4 acc2 = {0, 0, 0, 0}, acc3 = {0, 0, 0, 0};

#pragma unroll 4
    for (int ks = 0; ks < 32; ++ks) {
        i32x4 af  = *(const i32x4*)(aptr + (size_t)ks * 64);
        const signed char* bk = bbase + (size_t)ks * 1024;
        i32x4 bf0 = *(const i32x4*)(bk);
        i32x4 bf1 = *(const i32x4*)(bk + PLANE_STR);
        i32x4 bf2 = *(const i32x4*)(bk + 2 * PLANE_STR);
        i32x4 bf3 = *(const i32x4*)(bk + 3 * PLANE_STR);
        acc0 = __builtin_amdgcn_mfma_i32_16x16x64_i8(af, bf0, acc0, 0, 0, 0);
        acc1 = __builtin_amdgcn_mfma_i32_16x16x64_i8(af, bf1, acc1, 0, 0, 0);
        acc2 = __builtin_amdgcn_mfma_i32_16x16x64_i8(af, bf2, acc2, 0, 0, 0);
        acc3 = __builtin_amdgcn_mfma_i32_16x16x64_i8(af, bf3, acc3, 0, 0, 0);
    }

    // Epilogue: recombine planes exactly, fp64 membrane update, threshold.
    const float thrc = thresholds[c];
    const double thrd = (double)thrc;
    const double bvd  = (double)biases[c * N_DIM + n];
    signed char* spk_out = sig + (size_t)(((t + 1) & 1) * 4 + (c + 1)) * CH_BYTES;

#pragma unroll
    for (int r = 0; r < 4; ++r) {
        int b = w * 16 + ((l >> 4) << 2) + r;
        long long comb = ((long long)acc3[r] << 24) + ((long long)acc2[r] << 16)
                       + ((long long)acc1[r] << 8)  +  (long long)acc0[r];
        double inc = (double)comb * (1.0 / 8589934592.0);   // * 2^-33 (exact)
        size_t idx = ((size_t)(c * B_DIM + b)) * N_DIM + n;
        double m = memb[idx] + inc + bvd;
        bool spike = (thrd < m);
        if (spike) m -= thrd;
        memb[idx] = m;
        if (c < 3) {
            spk_out[(size_t)b * N_DIM + n] = spike ? 1 : 0;
        } else if (spike) {
            out[(size_t)b * N_DIM + n] += 0.0625f;          // 1/T, exact in fp32
        }
    }

    // Core-0 WGs (128 of them) generate next cycle's input spikes.
    if (c == 0 && (t + 1) < CYCLES) {
        int gtid = (wg << 8) + tid;          // 0..32767
        int e = gtid << 2;
        const float4 xv = *(const float4*)(x + e);
        uint32_t s = (uint32_t)in_spike(xv.x, t + 1)
                   | ((uint32_t)in_spike(xv.y, t + 1) << 8)
                   | ((uint32_t)in_spike(xv.z, t + 1) << 16)
                   | ((uint32_t)in_spike(xv.w, t + 1) << 24);
        *(uint32_t*)(sig + (size_t)(((t + 1) & 1) * 4) * CH_BYTES + e) = s;
    }
}

extern "C" void kernel_launch(void* const* d_in, const int* in_sizes, int n_in,
                              void* d_out, int out_size, void* d_ws, size_t ws_size,
                              hipStream_t stream) {
    const float* x       = (const float*)d_in[0];
    const float* wts     = (const float*)d_in[1];
    const float* biases  = (const float*)d_in[2];
    const float* thr     = (const float*)d_in[3];
    float* out           = (float*)d_out;

    signed char* wq   = (signed char*)d_ws;
    double*      memb = (double*)((char*)d_ws + MEMB_OFF);
    signed char* sig  = (signed char*)((char*)d_ws + SIG_OFF);

    // Zero state (harness poisons ws/out; we re-init every call).
    hipMemsetAsync((char*)d_ws + MEMB_OFF, 0, MEMB_BYTES + SIG_BYTES, stream);
    hipMemsetAsync(d_out, 0, (size_t)out_size * sizeof(float), stream);

    // Quantize + pack weights (deterministic, every call).
    pack_w<<<dim3(C_DIM * 32 * 128), dim3(64), 0, stream>>>(wts, wq);

    // Input spikes for cycle 0.
    gen_in<<<dim3(128), dim3(256), 0, stream>>>(x, sig, 0);

    // 20 simulation cycles.
    for (int t = 0; t < CYCLES; ++t) {
        cycle_k<<<dim3(512), dim3(256), 0, stream>>>(wq, x, biases, thr,
                                                     memb, sig, out, t);
    }
}

// Round 2
// 448.642 us; speedup vs baseline: 1.0282x; 1.0282x over previous
//
#include <hip/hip_runtime.h>
#include <cstdint>
#include <cstddef>

// SpikingHybridCoreFlow: 20-cycle spiking simulation.
// Strategy: exact fixed-point weights (4 x i8 planes, scale 2^-33),
// i8 MFMA integer GEMM (order-independent exact accumulation),
// fp64 membrane state. Spike trains replicated bit-exact in fp32.
//
// R2: 8-wave WGs (4 b-tiles x 2 K-halves, exact i32 LDS reduce) for 2x
// occupancy; plane-interleaved WQ layout (4KB per (c,ct,kstep) block) so the
// 4 plane fragments are one stream with immediate offsets.

#define N_DIM 2048
#define B_DIM 64
#define C_DIM 4
#define T_SIM 16
#define CYCLES 20

using i32x4 = __attribute__((ext_vector_type(4))) int;

// Workspace layout
//   WQ   : [C][128 coltiles][32 ksteps][4 planes][1024B] = 67,108,864 B
//   MEMB : [C][B][N] double                               =  4,194,304 B
//   SIG  : [2 ping-pong][4 channels][B*N] int8            =  1,048,576 B
static constexpr size_t WQ_BYTES   = (size_t)C_DIM * 128 * 32 * 4 * 1024;
static constexpr size_t MEMB_OFF   = WQ_BYTES;
static constexpr size_t MEMB_BYTES = (size_t)C_DIM * B_DIM * N_DIM * 8;
static constexpr size_t SIG_OFF    = MEMB_OFF + MEMB_BYTES;
static constexpr size_t SIG_BYTES  = (size_t)2 * 4 * B_DIM * N_DIM;
static constexpr size_t CH_BYTES   = (size_t)B_DIM * N_DIM;     // one channel

// ---------------------------------------------------------------------------
// Quantize w (fp32) -> int32 fixed point (scale 2^33) -> 4 balanced i8 planes.
// wv * 2^33 is a power-of-2 scale: exact in fp32; llrintf gives the exact
// round-to-nearest-even integer. Packed layout per (c,ct,ks) block: 4 planes
// x 1024B, byte index in plane = lane*16 + j, where
//   n = ct*16 + (lane&15), a = ks*64 + ((lane>>4)<<4) + j
// matching the MFMA i8 16x16x64 B-fragment.
// ---------------------------------------------------------------------------
__global__ __launch_bounds__(64) void pack_w(const float* __restrict__ w,
                                             signed char* __restrict__ wq) {
    int blk = blockIdx.x;              // c*32*128 + ks*128 + ct
    int ct  = blk & 127;
    int ks  = (blk >> 7) & 31;
    int c   = blk >> 12;
    int l   = threadIdx.x;             // 0..63
    int n     = ct * 16 + (l & 15);
    int abase = ks * 64 + ((l >> 4) << 4);
    const float* wc = w + (size_t)c * N_DIM * N_DIM;
    size_t blk_base = (((size_t)(c * 128 + ct) * 32 + ks) * 4) * 1024 + (size_t)l * 16;

    for (int j4 = 0; j4 < 4; ++j4) {
        uint32_t dw0 = 0, dw1 = 0, dw2 = 0, dw3 = 0;
        for (int i = 0; i < 4; ++i) {
            int a = abase + j4 * 4 + i;
            float wv = wc[(size_t)a * N_DIM + n];
            long long vi = llrintf(wv * 8589934592.0f);        // * 2^33, exact
            int v  = (int)vi;
            int b0 = (int)(signed char)(v & 255); v = (v - b0) >> 8;
            int b1 = (int)(signed char)(v & 255); v = (v - b1) >> 8;
            int b2 = (int)(signed char)(v & 255); v = (v - b2) >> 8;
            int b3 = v;                                        // fits in i8 by range
            dw0 |= (uint32_t)(uint8_t)b0 << (8 * i);
            dw1 |= (uint32_t)(uint8_t)b1 << (8 * i);
            dw2 |= (uint32_t)(uint8_t)b2 << (8 * i);
            dw3 |= (uint32_t)(uint8_t)b3 << (8 * i);
        }
        *(uint32_t*)(wq + blk_base +    0 + j4 * 4) = dw0;
        *(uint32_t*)(wq + blk_base + 1024 + j4 * 4) = dw1;
        *(uint32_t*)(wq + blk_base + 2048 + j4 * 4) = dw2;
        *(uint32_t*)(wq + blk_base + 3072 + j4 * 4) = dw3;
    }
}

// ---------------------------------------------------------------------------
// Bit-exact replication of _uniform_spikes (all ops IEEE fp32, like XLA):
// rintf == jnp.round (half-even), fmodf == lax.rem (exact for positives).
// ---------------------------------------------------------------------------
__device__ __forceinline__ int in_spike(float xv, int cycle) {
    if (cycle >= T_SIM) return 0;
    float n_spk = rintf(xv * 16.0f);
    if (n_spk == 16.0f) return 1;
    if (n_spk == 0.0f)  return 0;
    float spacing = 16.0f / n_spk;
    float cf = (float)cycle;
    float q = floorf(cf / spacing);
    float r = fmodf(cf, spacing);
    return (q < n_spk && floorf(r) == 0.0f) ? 1 : 0;
}

__global__ __launch_bounds__(256) void gen_in(const float* __restrict__ x,
                                              signed char* __restrict__ sig, int t) {
    int gtid = blockIdx.x * 256 + threadIdx.x;    // 0..32767
    int e = gtid << 2;
    const float4 xv = *(const float4*)(x + e);
    uint32_t s = (uint32_t)in_spike(xv.x, t)
               | ((uint32_t)in_spike(xv.y, t) << 8)
               | ((uint32_t)in_spike(xv.z, t) << 16)
               | ((uint32_t)in_spike(xv.w, t) << 24);
    *(uint32_t*)(sig + (size_t)(t & 1) * 4 * CH_BYTES + e) = s;
}

// ---------------------------------------------------------------------------
// One simulation cycle. Grid: 512 WGs = 4 cores x 128 col-tiles(16).
// 512 threads = 8 waves = 4 b-tiles x 2 K-halves. Each wave: 16 ksteps x
// 4-plane i8 MFMA into i32x4 accs. kh=1 partials added exactly via LDS.
// ---------------------------------------------------------------------------
__global__ __launch_bounds__(512, 4) void cycle_k(
        const signed char* __restrict__ wq, const float* __restrict__ x,
        const float* __restrict__ biases, const float* __restrict__ thresholds,
        double* __restrict__ memb, signed char* __restrict__ sig,
        float* __restrict__ out, int t)
{
    const int wg = blockIdx.x;
    const int c  = wg >> 7;
    const int ct = wg & 127;
    const int tid = threadIdx.x;
    const int wv  = tid >> 6;          // 0..7
    const int wb  = wv & 3;            // b-tile
    const int kh  = wv >> 2;           // K-half
    const int l   = tid & 63;
    const int n0  = ct << 4;
    const int n   = n0 + (l & 15);

    __shared__ int lred[4][16][64];    // [b-tile][reg (plane*4+r)][lane]

    // A operand: signals channel c, ping slot t&1, K-half kh.
    const signed char* A = sig + (size_t)((t & 1) * 4 + c) * CH_BYTES;
    const int arow = wb * 16 + (l & 15);
    const signed char* aptr = A + (size_t)arow * N_DIM + (size_t)kh * 1024
                            + ((l >> 4) << 4);
    // B operand: packed plane-interleaved blocks, 4096B per kstep.
    const signed char* bbase = wq
        + (((size_t)(c * 128 + ct) * 32 + (size_t)kh * 16) * 4) * 1024
        + (size_t)l * 16;

    i32x4 acc0 = {0, 0, 0, 0}, acc1 = {0, 0, 0, 0};
    i32x4 acc2 = {0, 0, 0, 0}, acc3 = {0, 0, 0, 0};

#pragma unroll 4
    for (int ks = 0; ks < 16; ++ks) {
        i32x4 af  = *(const i32x4*)(aptr + (size_t)ks * 64);
        const signed char* bk = bbase + (size_t)ks * 4096;
        i32x4 bf0 = *(const i32x4*)(bk);
        i32x4 bf1 = *(const i32x4*)(bk + 1024);
        i32x4 bf2 = *(const i32x4*)(bk + 2048);
        i32x4 bf3 = *(const i32x4*)(bk + 3072);
        acc0 = __builtin_amdgcn_mfma_i32_16x16x64_i8(af, bf0, acc0, 0, 0, 0);
        acc1 = __builtin_amdgcn_mfma_i32_16x16x64_i8(af, bf1, acc1, 0, 0, 0);
        acc2 = __builtin_amdgcn_mfma_i32_16x16x64_i8(af, bf2, acc2, 0, 0, 0);
        acc3 = __builtin_amdgcn_mfma_i32_16x16x64_i8(af, bf3, acc3, 0, 0, 0);
    }

    // Exact integer reduce of the two K-halves through LDS.
    if (kh == 1) {
#pragma unroll
        for (int r = 0; r < 4; ++r) {
            lred[wb][ 0 + r][l] = acc0[r];
            lred[wb][ 4 + r][l] = acc1[r];
            lred[wb][ 8 + r][l] = acc2[r];
            lred[wb][12 + r][l] = acc3[r];
        }
    }
    __syncthreads();
    if (kh == 0) {
#pragma unroll
        for (int r = 0; r < 4; ++r) {
            acc0[r] += lred[wb][ 0 + r][l];
            acc1[r] += lred[wb][ 4 + r][l];
            acc2[r] += lred[wb][ 8 + r][l];
            acc3[r] += lred[wb][12 + r][l];
        }

        // Epilogue: recombine planes exactly, fp64 membrane update, threshold.
        const double thrd = (double)thresholds[c];
        const double bvd  = (double)biases[c * N_DIM + n];
        signed char* spk_out = sig + (size_t)(((t + 1) & 1) * 4 + (c + 1)) * CH_BYTES;

#pragma unroll
        for (int r = 0; r < 4; ++r) {
            int b = wb * 16 + ((l >> 4) << 2) + r;
            long long comb = ((long long)acc3[r] << 24) + ((long long)acc2[r] << 16)
                           + ((long long)acc1[r] << 8)  +  (long long)acc0[r];
            double inc = (double)comb * (1.0 / 8589934592.0);   // * 2^-33 (exact)
            size_t idx = ((size_t)(c * B_DIM + b)) * N_DIM + n;
            double m = memb[idx] + inc + bvd;
            bool spike = (thrd < m);
            if (spike) m -= thrd;
            memb[idx] = m;
            if (c < 3) {
                spk_out[(size_t)b * N_DIM + n] = spike ? 1 : 0;
            } else if (spike) {
                out[(size_t)b * N_DIM + n] += 0.0625f;          // 1/T, exact
            }
        }
    }

    // Core-0 WGs (128 of them) generate next cycle's input spikes.
    if (c == 0 && tid < 256 && (t + 1) < CYCLES) {
        int gtid = (wg << 8) + tid;          // 0..32767
        int e = gtid << 2;
        const float4 xv = *(const float4*)(x + e);
        uint32_t s = (uint32_t)in_spike(xv.x, t + 1)
                   | ((uint32_t)in_spike(xv.y, t + 1) << 8)
                   | ((uint32_t)in_spike(xv.z, t + 1) << 16)
                   | ((uint32_t)in_spike(xv.w, t + 1) << 24);
        *(uint32_t*)(sig + (size_t)(((t + 1) & 1) * 4) * CH_BYTES + e) = s;
    }
}

extern "C" void kernel_launch(void* const* d_in, const int* in_sizes, int n_in,
                              void* d_out, int out_size, void* d_ws, size_t ws_size,
                              hipStream_t stream) {
    const float* x       = (const float*)d_in[0];
    const float* wts     = (const float*)d_in[1];
    const float* biases  = (const float*)d_in[2];
    const float* thr     = (const float*)d_in[3];
    float* out           = (float*)d_out;

    signed char* wq   = (signed char*)d_ws;
    double*      memb = (double*)((char*)d_ws + MEMB_OFF);
    signed char* sig  = (signed char*)((char*)d_ws + SIG_OFF);

    // Zero state (harness poisons ws/out; we re-init every call).
    hipMemsetAsync((char*)d_ws + MEMB_OFF, 0, MEMB_BYTES + SIG_BYTES, stream);
    hipMemsetAsync(d_out, 0, (size_t)out_size * sizeof(float), stream);

    // Quantize + pack weights (deterministic, every call).
    pack_w<<<dim3(C_DIM * 32 * 128), dim3(64), 0, stream>>>(wts, wq);

    // Input spikes for cycle 0.
    gen_in<<<dim3(128), dim3(256), 0, stream>>>(x, sig, 0);

    // 20 simulation cycles.
    for (int t = 0; t < CYCLES; ++t) {
        cycle_k<<<dim3(512), dim3(512), 0, stream>>>(wq, x, biases, thr,
                                                     memb, sig, out, t);
    }
}

// Round 3
// 269.700 us; speedup vs baseline: 1.7104x; 1.6635x over previous
//
#include <hip/hip_runtime.h>
#include <cstdint>
#include <cstddef>

// SpikingHybridCoreFlow: 20-cycle spiking simulation.
// Exactness strategy (unchanged): fixed-point weights (4 x i8 planes, scale
// 2^-33), i8 MFMA integer GEMM (order-independent exact), fp64 membrane.
//
// R3: BATCHED PIPELINE restructure. Core c's GEMM inputs for ALL cycles are
// known once core c-1 finished -> 4 stages of {M=1280 batched GEMM -> scan}.
// W is read once per core (LDS-staged) instead of 20x  => kills the ~3.3TB/s
// W-restream wall that made cycle_k ~20us regardless of occupancy.

#define N_DIM 2048
#define B_DIM 64
#define C_DIM 4
#define T_SIM 16
#define CYCLES 20
#define M_ROWS (CYCLES * B_DIM)          // 1280

using i32x4 = __attribute__((ext_vector_type(4))) int;

// Workspace layout
//   WQ    : [C][128 strips][32 ksteps][4 planes][1024B] = 67,108,864 B
//   DELTA : [M_ROWS][N] double                           = 20,971,520 B
//   SIG   : 4 x [M_ROWS][N] int8 spike/A matrices        = 10,485,760 B
static constexpr size_t WQ_BYTES    = (size_t)C_DIM * 128 * 32 * 4 * 1024;
static constexpr size_t DELTA_OFF   = WQ_BYTES;
static constexpr size_t DELTA_BYTES = (size_t)M_ROWS * N_DIM * 8;
static constexpr size_t SIG_OFF     = DELTA_OFF + DELTA_BYTES;
static constexpr size_t AMAT_BYTES  = (size_t)M_ROWS * N_DIM;
static constexpr size_t SIG_BYTES   = (size_t)4 * AMAT_BYTES;

// ---------------------------------------------------------------------------
// Quantize w (fp32) -> int32 fixed point (scale 2^33) -> 4 balanced i8 planes.
// Layout per (c,ct,ks) block: 4 planes x 1024B; in-plane byte = lane*16 + j:
//   n = ct*16 + (lane&15), k = ks*64 + ((lane>>4)<<4) + j   (B-fragment order)
// ---------------------------------------------------------------------------
__global__ __launch_bounds__(64) void pack_w(const float* __restrict__ w,
                                             signed char* __restrict__ wq) {
    int blk = blockIdx.x;              // c*32*128 + ks*128 + ct
    int ct  = blk & 127;
    int ks  = (blk >> 7) & 31;
    int c   = blk >> 12;
    int l   = threadIdx.x;             // 0..63
    int n     = ct * 16 + (l & 15);
    int abase = ks * 64 + ((l >> 4) << 4);
    const float* wc = w + (size_t)c * N_DIM * N_DIM;
    size_t blk_base = (((size_t)(c * 128 + ct) * 32 + ks) * 4) * 1024 + (size_t)l * 16;

    for (int j4 = 0; j4 < 4; ++j4) {
        uint32_t dw0 = 0, dw1 = 0, dw2 = 0, dw3 = 0;
        for (int i = 0; i < 4; ++i) {
            int a = abase + j4 * 4 + i;
            float wv = wc[(size_t)a * N_DIM + n];
            long long vi = llrintf(wv * 8589934592.0f);        // * 2^33, exact
            int v  = (int)vi;
            int b0 = (int)(signed char)(v & 255); v = (v - b0) >> 8;
            int b1 = (int)(signed char)(v & 255); v = (v - b1) >> 8;
            int b2 = (int)(signed char)(v & 255); v = (v - b2) >> 8;
            int b3 = v;
            dw0 |= (uint32_t)(uint8_t)b0 << (8 * i);
            dw1 |= (uint32_t)(uint8_t)b1 << (8 * i);
            dw2 |= (uint32_t)(uint8_t)b2 << (8 * i);
            dw3 |= (uint32_t)(uint8_t)b3 << (8 * i);
        }
        *(uint32_t*)(wq + blk_base +    0 + j4 * 4) = dw0;
        *(uint32_t*)(wq + blk_base + 1024 + j4 * 4) = dw1;
        *(uint32_t*)(wq + blk_base + 2048 + j4 * 4) = dw2;
        *(uint32_t*)(wq + blk_base + 3072 + j4 * 4) = dw3;
    }
}

// ---------------------------------------------------------------------------
// Bit-exact replication of _uniform_spikes (IEEE fp32, like XLA).
// ---------------------------------------------------------------------------
__device__ __forceinline__ int in_spike(float xv, int cycle) {
    if (cycle >= T_SIM) return 0;
    float n_spk = rintf(xv * 16.0f);
    if (n_spk == 16.0f) return 1;
    if (n_spk == 0.0f)  return 0;
    float spacing = 16.0f / n_spk;
    float cf = (float)cycle;
    float q = floorf(cf / spacing);
    float r = fmodf(cf, spacing);
    return (q < n_spk && floorf(r) == 0.0f) ? 1 : 0;
}

// Build core-0 A matrix for all cycles: A0[t*64+b][n] = in_spike(x[b][n], t).
__global__ __launch_bounds__(256) void gen_in_all(const float* __restrict__ x,
                                                  signed char* __restrict__ a0) {
    int gid = blockIdx.x * 256 + threadIdx.x;      // 0 .. 655359
    int e   = gid << 2;                            // byte index
    int row = e >> 11;                             // t*64 + b
    int t = row >> 6, b = row & 63;
    int n0 = e & 2047;
    const float4 xv = *(const float4*)(x + (size_t)b * N_DIM + n0);
    uint32_t s = (uint32_t)in_spike(xv.x, t)
               | ((uint32_t)in_spike(xv.y, t) << 8)
               | ((uint32_t)in_spike(xv.z, t) << 16)
               | ((uint32_t)in_spike(xv.w, t) << 24);
    *(uint32_t*)(a0 + e) = s;
}

// ---------------------------------------------------------------------------
// Batched GEMM for one core: Delta[m][n] = sum_k A[m][k] * W[k][n], exact.
// Grid 256 WGs = 2 m-halves x 128 n-strips (wg = h*128 + s so both halves of
// a strip share an XCD slot under round-robin). 512 threads = 8 waves; wave
// owns 5 m-tiles of 16 rows. B strip (128KB) LDS-staged in 4 x 32KB chunks,
// double-buffered via global_load_lds(16B).
// ---------------------------------------------------------------------------
__global__ __launch_bounds__(512) void gemm_core(
        const signed char* __restrict__ wq, const signed char* __restrict__ A,
        double* __restrict__ delta, int c)
{
    __shared__ __align__(16) signed char lds[2][32768];
    const int wg  = blockIdx.x;
    const int s   = wg & 127;          // n-strip (16 cols)
    const int h   = wg >> 7;           // m-half (640 rows)
    const int tid = threadIdx.x;
    const int wv  = tid >> 6;          // 0..7
    const int l   = tid & 63;

    const signed char* wsrc = wq + ((size_t)(c * 128 + s) * 32) * 4096;
    const int stage_off = (wv << 10) + (l << 4);   // within 8KB issue block

    // A addressing: lane row = h*640 + wv*80 + j*16 + (l&15); k-offset (l>>4)*16.
    const signed char* abase = A + (size_t)(h * 640 + wv * 80 + (l & 15)) * N_DIM
                             + ((l >> 4) << 4);

    i32x4 acc[5][4];
#pragma unroll
    for (int j = 0; j < 5; ++j)
#pragma unroll
        for (int p = 0; p < 4; ++p) acc[j][p] = i32x4{0, 0, 0, 0};

    // STAGE chunk ch into buffer buf: 32KB = 4 issues x (8 waves x 64 lanes x 16B).
    auto STAGE = [&](int buf, int ch) {
#pragma unroll
        for (int i = 0; i < 4; ++i) {
            const signed char* src = wsrc + (size_t)ch * 32768 + i * 8192 + stage_off;
            __builtin_amdgcn_global_load_lds(
                (const __attribute__((address_space(1))) uint32_t*)src,
                (__attribute__((address_space(3))) uint32_t*)(&lds[buf][i * 8192 + (wv << 10)]),
                16, 0, 0);
        }
    };

    STAGE(0, 0);
    __syncthreads();                               // drains vmcnt(0)
    int cur = 0;

    for (int ch = 0; ch < 4; ++ch) {
        if (ch < 3) STAGE(cur ^ 1, ch + 1);
        const signed char* lb = &lds[cur][l << 4];
#pragma unroll
        for (int k8 = 0; k8 < 8; ++k8) {
            i32x4 bf0 = *(const i32x4*)(lb + k8 * 4096);
            i32x4 bf1 = *(const i32x4*)(lb + k8 * 4096 + 1024);
            i32x4 bf2 = *(const i32x4*)(lb + k8 * 4096 + 2048);
            i32x4 bf3 = *(const i32x4*)(lb + k8 * 4096 + 3072);
            const int kb = (ch * 8 + k8) * 64;
#pragma unroll
            for (int j = 0; j < 5; ++j) {
                i32x4 af = *(const i32x4*)(abase + (size_t)j * 16 * N_DIM + kb);
                acc[j][0] = __builtin_amdgcn_mfma_i32_16x16x64_i8(af, bf0, acc[j][0], 0, 0, 0);
                acc[j][1] = __builtin_amdgcn_mfma_i32_16x16x64_i8(af, bf1, acc[j][1], 0, 0, 0);
                acc[j][2] = __builtin_amdgcn_mfma_i32_16x16x64_i8(af, bf2, acc[j][2], 0, 0, 0);
                acc[j][3] = __builtin_amdgcn_mfma_i32_16x16x64_i8(af, bf3, acc[j][3], 0, 0, 0);
            }
        }
        __syncthreads();                           // stage landed + LDS reads done
        cur ^= 1;
    }

    // Epilogue: combine planes exactly -> fp64 increments.
    const int n = (s << 4) + (l & 15);
#pragma unroll
    for (int j = 0; j < 5; ++j) {
#pragma unroll
        for (int r = 0; r < 4; ++r) {
            int row = h * 640 + wv * 80 + j * 16 + ((l >> 4) << 2) + r;
            long long comb = ((long long)acc[j][3][r] << 24) + ((long long)acc[j][2][r] << 16)
                           + ((long long)acc[j][1][r] << 8)  +  (long long)acc[j][0][r];
            delta[(size_t)row * N_DIM + n] = (double)comb * (1.0 / 8589934592.0);
        }
    }
}

// ---------------------------------------------------------------------------
// Sequential threshold scan for one core: membrane in a register, 20 steps.
// Emits next core's A matrix (spikes at t feed cycle t+1), or the output.
// ---------------------------------------------------------------------------
__global__ __launch_bounds__(256) void scan_core(
        const double* __restrict__ delta, const float* __restrict__ biases,
        const float* __restrict__ thresholds, signed char* __restrict__ a_next,
        float* __restrict__ out, int c)
{
    int gid = blockIdx.x * 256 + threadIdx.x;      // 0..131071
    int b = gid >> 11, n = gid & 2047;
    const double bv = (double)biases[c * N_DIM + n];
    const double th = (double)thresholds[c];
    double m = 0.0;
    float cnt = 0.0f;
    for (int t = 0; t < CYCLES; ++t) {
        m = m + delta[(size_t)(t * 64 + b) * N_DIM + n] + bv;
        bool sp = (th < m);
        if (sp) m -= th;
        if (c < 3) {
            if (t + 1 < CYCLES)
                a_next[(size_t)((t + 1) * 64 + b) * N_DIM + n] = sp ? 1 : 0;
        } else if (sp) {
            cnt += 1.0f;
        }
    }
    if (c == 3) out[(size_t)b * N_DIM + n] = cnt * 0.0625f;   // /16, exact
}

extern "C" void kernel_launch(void* const* d_in, const int* in_sizes, int n_in,
                              void* d_out, int out_size, void* d_ws, size_t ws_size,
                              hipStream_t stream) {
    const float* x       = (const float*)d_in[0];
    const float* wts     = (const float*)d_in[1];
    const float* biases  = (const float*)d_in[2];
    const float* thr     = (const float*)d_in[3];
    float* out           = (float*)d_out;

    signed char* wq    = (signed char*)d_ws;
    double*      delta = (double*)((char*)d_ws + DELTA_OFF);
    signed char* sig   = (signed char*)((char*)d_ws + SIG_OFF);

    // Zero spike matrices (row t=0 of each must be zero; ws is poisoned).
    hipMemsetAsync(sig, 0, SIG_BYTES, stream);

    // Quantize + pack weights; build core-0 inputs for all cycles.
    pack_w<<<dim3(C_DIM * 32 * 128), dim3(64), 0, stream>>>(wts, wq);
    gen_in_all<<<dim3(M_ROWS * N_DIM / 4 / 256), dim3(256), 0, stream>>>(x, sig);

    // 4 pipeline stages: batched GEMM (exact) -> threshold scan.
    for (int c = 0; c < C_DIM; ++c) {
        const signed char* a_cur = sig + (size_t)c * AMAT_BYTES;
        signed char* a_nxt = (c < 3) ? (signed char*)(sig + (size_t)(c + 1) * AMAT_BYTES)
                                     : (signed char*)sig;   // unused for c==3
        gemm_core<<<dim3(256), dim3(512), 0, stream>>>(wq, a_cur, delta, c);
        scan_core<<<dim3(512), dim3(256), 0, stream>>>(delta, biases, thr,
                                                       a_nxt, out, c);
    }
}

// Round 4
// 167.793 us; speedup vs baseline: 2.7492x; 1.6073x over previous
//
#include <hip/hip_runtime.h>
#include <cstdint>
#include <cstddef>

// SpikingHybridCoreFlow: 20-cycle spiking simulation.
// Exactness strategy (unchanged): fixed-point weights (4 x i8 planes, scale
// 2^-33), i8 MFMA integer GEMM (order-independent exact), fp64 membrane.
//
// R4: A (spike matrices) now stored in MFMA-fragment-packed layout (1KB
// blocks, byte = lane*16+j) -- produced for free by gen_in_all/scan_core.
// gemm_core LDS-stages BOTH operands via global_load_lds(16B) with a 2-phase
// pipelined k-loop (stage k+1 before compute k), killing the synchronous
// global A-load latency that held R3's gemm at 50us (floor ~11us).

#define N_DIM 2048
#define B_DIM 64
#define C_DIM 4
#define T_SIM 16
#define CYCLES 20
#define M_ROWS (CYCLES * B_DIM)          // 1280

using i32x4 = __attribute__((ext_vector_type(4))) int;

// Workspace layout
//   WQ    : [C][128 strips][32 ksteps][4 planes][1024B] = 67,108,864 B
//   DELTA : [M_ROWS][N] double                           = 20,971,520 B
//   SIG   : 4 x packed A matrices [80 mt][32 ks][1024B]  = 10,485,760 B
static constexpr size_t WQ_BYTES    = (size_t)C_DIM * 128 * 32 * 4 * 1024;
static constexpr size_t DELTA_OFF   = WQ_BYTES;
static constexpr size_t DELTA_BYTES = (size_t)M_ROWS * N_DIM * 8;
static constexpr size_t SIG_OFF     = DELTA_OFF + DELTA_BYTES;
static constexpr size_t AMAT_BYTES  = (size_t)M_ROWS * N_DIM;    // 2.5 MB packed
static constexpr size_t SIG_BYTES   = (size_t)4 * AMAT_BYTES;

// Packed-A byte offset for logical (m, k):
//   block = (m>>4)*32 + (k>>6); in-block = ((k>>4)&3)*256 + (m&15)*16 + (k&15)
// which is exactly the i8 16x16x64 A-fragment order (lane*16 + j).
__device__ __forceinline__ size_t apk_off(int m, int k) {
    return ((size_t)((m >> 4) * 32 + (k >> 6)) << 10)
         + (size_t)((((k >> 4) & 3) << 8) + ((m & 15) << 4) + (k & 15));
}

// ---------------------------------------------------------------------------
// Quantize w (fp32) -> int32 fixed point (scale 2^33) -> 4 balanced i8 planes.
// Layout per (c,ct,ks) block: 4 planes x 1024B; in-plane byte = lane*16 + j:
//   n = ct*16 + (lane&15), k = ks*64 + ((lane>>4)<<4) + j   (B-fragment order)
// ---------------------------------------------------------------------------
__global__ __launch_bounds__(64) void pack_w(const float* __restrict__ w,
                                             signed char* __restrict__ wq) {
    int blk = blockIdx.x;              // c*32*128 + ks*128 + ct
    int ct  = blk & 127;
    int ks  = (blk >> 7) & 31;
    int c   = blk >> 12;
    int l   = threadIdx.x;             // 0..63
    int n     = ct * 16 + (l & 15);
    int abase = ks * 64 + ((l >> 4) << 4);
    const float* wc = w + (size_t)c * N_DIM * N_DIM;
    size_t blk_base = (((size_t)(c * 128 + ct) * 32 + ks) * 4) * 1024 + (size_t)l * 16;

    for (int j4 = 0; j4 < 4; ++j4) {
        uint32_t dw0 = 0, dw1 = 0, dw2 = 0, dw3 = 0;
        for (int i = 0; i < 4; ++i) {
            int a = abase + j4 * 4 + i;
            float wv = wc[(size_t)a * N_DIM + n];
            long long vi = llrintf(wv * 8589934592.0f);        // * 2^33, exact
            int v  = (int)vi;
            int b0 = (int)(signed char)(v & 255); v = (v - b0) >> 8;
            int b1 = (int)(signed char)(v & 255); v = (v - b1) >> 8;
            int b2 = (int)(signed char)(v & 255); v = (v - b2) >> 8;
            int b3 = v;
            dw0 |= (uint32_t)(uint8_t)b0 << (8 * i);
            dw1 |= (uint32_t)(uint8_t)b1 << (8 * i);
            dw2 |= (uint32_t)(uint8_t)b2 << (8 * i);
            dw3 |= (uint32_t)(uint8_t)b3 << (8 * i);
        }
        *(uint32_t*)(wq + blk_base +    0 + j4 * 4) = dw0;
        *(uint32_t*)(wq + blk_base + 1024 + j4 * 4) = dw1;
        *(uint32_t*)(wq + blk_base + 2048 + j4 * 4) = dw2;
        *(uint32_t*)(wq + blk_base + 3072 + j4 * 4) = dw3;
    }
}

// ---------------------------------------------------------------------------
// Bit-exact replication of _uniform_spikes (IEEE fp32, like XLA).
// ---------------------------------------------------------------------------
__device__ __forceinline__ int in_spike(float xv, int cycle) {
    if (cycle >= T_SIM) return 0;
    float n_spk = rintf(xv * 16.0f);
    if (n_spk == 16.0f) return 1;
    if (n_spk == 0.0f)  return 0;
    float spacing = 16.0f / n_spk;
    float cf = (float)cycle;
    float q = floorf(cf / spacing);
    float r = fmodf(cf, spacing);
    return (q < n_spk && floorf(r) == 0.0f) ? 1 : 0;
}

// Build packed core-0 A matrix: A0[t*64+b][n] = in_spike(x[b][n], t).
__global__ __launch_bounds__(256) void gen_in_all(const float* __restrict__ x,
                                                  signed char* __restrict__ a0) {
    int gid = blockIdx.x * 256 + threadIdx.x;      // 0 .. 655359
    int e   = gid << 2;                            // logical [m][k] byte index
    int row = e >> 11;                             // t*64 + b
    int t = row >> 6, b = row & 63;
    int n0 = e & 2047;
    const float4 xv = *(const float4*)(x + (size_t)b * N_DIM + n0);
    uint32_t s = (uint32_t)in_spike(xv.x, t)
               | ((uint32_t)in_spike(xv.y, t) << 8)
               | ((uint32_t)in_spike(xv.z, t) << 16)
               | ((uint32_t)in_spike(xv.w, t) << 24);
    *(uint32_t*)(a0 + apk_off(row, n0)) = s;       // 4 consecutive bytes, aligned
}

// ---------------------------------------------------------------------------
// Batched GEMM for one core: Delta[m][n] = sum_k A[m][k] * W[k][n], exact.
// Grid 512 WGs = 4 m-quarters x 128 n-strips (wg = q*128 + s: each XCD's B
// working set ~2MB, L2-fit). 256 threads = 4 waves; wave owns 5 m-tiles.
// Per kstep: stage 20KB A + 4KB B (24 DMA wave-loads) into LDS[buf^1] BEFORE
// computing LDS[buf] (20 MFMAs/wave); one barrier per kstep. 48KB LDS ->
// 2 WGs/CU co-resident, cross-WG overlap hides the barrier drain.
// ---------------------------------------------------------------------------
__global__ __launch_bounds__(256, 2) void gemm_core(
        const signed char* __restrict__ wq, const signed char* __restrict__ apk,
        double* __restrict__ delta, int c)
{
    __shared__ __align__(16) signed char lds[2][24 * 1024];
    const int wg  = blockIdx.x;
    const int q   = wg >> 7;           // m-quarter (20 m-tiles)
    const int s   = wg & 127;          // n-strip (16 cols)
    const int tid = threadIdx.x;
    const int wv  = tid >> 6;          // 0..3
    const int l   = tid & 63;

    const signed char* bsrc = wq + ((size_t)(c * 128 + s) * 32) * 4096;
    const signed char* asrc = apk + ((size_t)(q * 20) * 32) * 1024;

    // Stage slice ks into lds[buf]: A tiles 0..19 (waves round-robin) + B planes.
    auto STAGE = [&](int buf, int ks) {
#pragma unroll
        for (int r = 0; r < 5; ++r) {
            int lt = r * 4 + wv;
            __builtin_amdgcn_global_load_lds(
                (const __attribute__((address_space(1))) uint32_t*)
                    (asrc + ((size_t)lt * 32 + ks) * 1024 + l * 16),
                (__attribute__((address_space(3))) uint32_t*)(&lds[buf][lt * 1024]),
                16, 0, 0);
        }
        __builtin_amdgcn_global_load_lds(
            (const __attribute__((address_space(1))) uint32_t*)
                (bsrc + (size_t)ks * 4096 + wv * 1024 + l * 16),
            (__attribute__((address_space(3))) uint32_t*)(&lds[buf][20 * 1024 + wv * 1024]),
            16, 0, 0);
    };

    i32x4 acc[5][4];
#pragma unroll
    for (int j = 0; j < 5; ++j)
#pragma unroll
        for (int p = 0; p < 4; ++p) acc[j][p] = i32x4{0, 0, 0, 0};

    STAGE(0, 0);
    __syncthreads();                               // drain vmcnt, slice 0 ready
    int cur = 0;

    for (int ks = 0; ks < 32; ++ks) {
        if (ks < 31) STAGE(cur ^ 1, ks + 1);       // issue next slice early
        const signed char* lb = &lds[cur][(size_t)l * 16];
        i32x4 bf0 = *(const i32x4*)(lb + 20 * 1024);
        i32x4 bf1 = *(const i32x4*)(lb + 21 * 1024);
        i32x4 bf2 = *(const i32x4*)(lb + 22 * 1024);
        i32x4 bf3 = *(const i32x4*)(lb + 23 * 1024);
#pragma unroll
        for (int j = 0; j < 5; ++j) {
            i32x4 af = *(const i32x4*)(lb + (wv * 5 + j) * 1024);
            acc[j][0] = __builtin_amdgcn_mfma_i32_16x16x64_i8(af, bf0, acc[j][0], 0, 0, 0);
            acc[j][1] = __builtin_amdgcn_mfma_i32_16x16x64_i8(af, bf1, acc[j][1], 0, 0, 0);
            acc[j][2] = __builtin_amdgcn_mfma_i32_16x16x64_i8(af, bf2, acc[j][2], 0, 0, 0);
            acc[j][3] = __builtin_amdgcn_mfma_i32_16x16x64_i8(af, bf3, acc[j][3], 0, 0, 0);
        }
        __syncthreads();                           // stage landed + reads done
        cur ^= 1;
    }

    // Epilogue: combine planes exactly -> fp64 increments.
    const int n = (s << 4) + (l & 15);
#pragma unroll
    for (int j = 0; j < 5; ++j) {
#pragma unroll
        for (int r = 0; r < 4; ++r) {
            int row = (q * 20 + wv * 5 + j) * 16 + ((l >> 4) << 2) + r;
            long long comb = ((long long)acc[j][3][r] << 24) + ((long long)acc[j][2][r] << 16)
                           + ((long long)acc[j][1][r] << 8)  +  (long long)acc[j][0][r];
            delta[(size_t)row * N_DIM + n] = (double)comb * (1.0 / 8589934592.0);
        }
    }
}

// ---------------------------------------------------------------------------
// Sequential threshold scan for one core: membrane in a register, 20 steps.
// Emits next core's packed A matrix (spikes at t feed cycle t+1), or output.
// ---------------------------------------------------------------------------
__global__ __launch_bounds__(256) void scan_core(
        const double* __restrict__ delta, const float* __restrict__ biases,
        const float* __restrict__ thresholds, signed char* __restrict__ a_next,
        float* __restrict__ out, int c)
{
    int gid = blockIdx.x * 256 + threadIdx.x;      // 0..131071
    int b = gid >> 11, n = gid & 2047;
    const double bv = (double)biases[c * N_DIM + n];
    const double th = (double)thresholds[c];
    double m = 0.0;
    float cnt = 0.0f;
    for (int t = 0; t < CYCLES; ++t) {
        m = m + delta[(size_t)(t * 64 + b) * N_DIM + n] + bv;
        bool sp = (th < m);
        if (sp) m -= th;
        if (c < 3) {
            if (t + 1 < CYCLES)
                a_next[apk_off((t + 1) * 64 + b, n)] = sp ? 1 : 0;
        } else if (sp) {
            cnt += 1.0f;
        }
    }
    if (c == 3) out[(size_t)b * N_DIM + n] = cnt * 0.0625f;   // /16, exact
}

extern "C" void kernel_launch(void* const* d_in, const int* in_sizes, int n_in,
                              void* d_out, int out_size, void* d_ws, size_t ws_size,
                              hipStream_t stream) {
    const float* x       = (const float*)d_in[0];
    const float* wts     = (const float*)d_in[1];
    const float* biases  = (const float*)d_in[2];
    const float* thr     = (const float*)d_in[3];
    float* out           = (float*)d_out;

    signed char* wq    = (signed char*)d_ws;
    double*      delta = (double*)((char*)d_ws + DELTA_OFF);
    signed char* sig   = (signed char*)((char*)d_ws + SIG_OFF);

    // Zero packed spike matrices (t=0 rows must be zero; ws is poisoned).
    hipMemsetAsync(sig, 0, SIG_BYTES, stream);

    // Quantize + pack weights; build packed core-0 inputs for all cycles.
    pack_w<<<dim3(C_DIM * 32 * 128), dim3(64), 0, stream>>>(wts, wq);
    gen_in_all<<<dim3(M_ROWS * N_DIM / 4 / 256), dim3(256), 0, stream>>>(x, sig);

    // 4 pipeline stages: batched GEMM (exact) -> threshold scan.
    for (int c = 0; c < C_DIM; ++c) {
        const signed char* a_cur = sig + (size_t)c * AMAT_BYTES;
        signed char* a_nxt = (c < 3) ? (signed char*)(sig + (size_t)(c + 1) * AMAT_BYTES)
                                     : (signed char*)sig;   // unused for c==3
        gemm_core<<<dim3(512), dim3(256), 0, stream>>>(wq, a_cur, delta, c);
        scan_core<<<dim3(512), dim3(256), 0, stream>>>(delta, biases, thr,
                                                       a_nxt, out, c);
    }
}

// Round 5
// 141.169 us; speedup vs baseline: 3.2677x; 1.1886x over previous
//
#include <hip/hip_runtime.h>
#include <cstdint>
#include <cstddef>

// SpikingHybridCoreFlow: 20-cycle spiking simulation.
// Exactness strategy (unchanged): fixed-point weights (4 x i8 planes, scale
// 2^-33), i8 MFMA integer GEMM (order-independent exact), fp64 membrane.
//
// R5: (a) A-matrix rows reordered to m = b*20 + t so each gemm WG owns full
// t-ranges -> threshold scan FUSED into gemm epilogue via LDS transpose
// (delta buffer + scan_core launches eliminated). (b) hipMemsetAsync(10MB)
// removed (runtime fill kernel cost ~38us/replay!) -- t=0 rows are zeroed by
// the producer. (c) pack_w stores coalesced dwordx4 (was stride-16 dwords).

#define N_DIM 2048
#define B_DIM 64
#define C_DIM 4
#define T_SIM 16
#define CYCLES 20
#define M_ROWS (CYCLES * B_DIM)          // 1280

using i32x4 = __attribute__((ext_vector_type(4))) int;
using u32x4 = __attribute__((ext_vector_type(4))) uint32_t;

// Workspace layout
//   WQ  : [C][128 strips][32 ksteps][4 planes][1024B] = 67,108,864 B
//   SIG : 4 x packed A matrices [80 mt][32 ks][1024B]  = 10,485,760 B
static constexpr size_t WQ_BYTES   = (size_t)C_DIM * 128 * 32 * 4 * 1024;
static constexpr size_t SIG_OFF    = WQ_BYTES;
static constexpr size_t AMAT_BYTES = (size_t)M_ROWS * N_DIM;

// Packed-A byte offset for logical (m, k); m = b*20 + t.
//   block = (m>>4)*32 + (k>>6); in-block = ((k>>4)&3)*256 + (m&15)*16 + (k&15)
// = the i8 16x16x64 A-fragment order (lane*16 + j).
__device__ __forceinline__ size_t apk_off(int m, int k) {
    return ((size_t)((m >> 4) * 32 + (k >> 6)) << 10)
         + (size_t)((((k >> 4) & 3) << 8) + ((m & 15) << 4) + (k & 15));
}

// ---------------------------------------------------------------------------
// Quantize w (fp32) -> int32 fixed point (scale 2^33) -> 4 balanced i8 planes.
// Layout per (c,ct,ks) block: 4 planes x 1024B; in-plane byte = lane*16 + j:
//   n = ct*16 + (lane&15), k = ks*64 + ((lane>>4)<<4) + j   (B-fragment order)
// Thread accumulates 16 bytes/plane -> one dwordx4 store per plane (coalesced).
// ---------------------------------------------------------------------------
__global__ __launch_bounds__(64) void pack_w(const float* __restrict__ w,
                                             signed char* __restrict__ wq) {
    int blk = blockIdx.x;              // c*32*128 + ks*128 + ct
    int ct  = blk & 127;
    int ks  = (blk >> 7) & 31;
    int c   = blk >> 12;
    int l   = threadIdx.x;             // 0..63
    int n     = ct * 16 + (l & 15);
    int abase = ks * 64 + ((l >> 4) << 4);
    const float* wc = w + (size_t)c * N_DIM * N_DIM;
    size_t blk_base = (((size_t)(c * 128 + ct) * 32 + ks) * 4) * 1024 + (size_t)l * 16;

    u32x4 d0, d1, d2, d3;
    for (int j4 = 0; j4 < 4; ++j4) {
        uint32_t w0 = 0, w1 = 0, w2 = 0, w3 = 0;
        for (int i = 0; i < 4; ++i) {
            int a = abase + j4 * 4 + i;
            float wv = wc[(size_t)a * N_DIM + n];
            long long vi = llrintf(wv * 8589934592.0f);        // * 2^33, exact
            int v  = (int)vi;
            int b0 = (int)(signed char)(v & 255); v = (v - b0) >> 8;
            int b1 = (int)(signed char)(v & 255); v = (v - b1) >> 8;
            int b2 = (int)(signed char)(v & 255); v = (v - b2) >> 8;
            int b3 = v;
            w0 |= (uint32_t)(uint8_t)b0 << (8 * i);
            w1 |= (uint32_t)(uint8_t)b1 << (8 * i);
            w2 |= (uint32_t)(uint8_t)b2 << (8 * i);
            w3 |= (uint32_t)(uint8_t)b3 << (8 * i);
        }
        d0[j4] = w0; d1[j4] = w1; d2[j4] = w2; d3[j4] = w3;
    }
    *(u32x4*)(wq + blk_base)        = d0;
    *(u32x4*)(wq + blk_base + 1024) = d1;
    *(u32x4*)(wq + blk_base + 2048) = d2;
    *(u32x4*)(wq + blk_base + 3072) = d3;
}

// ---------------------------------------------------------------------------
// Bit-exact replication of _uniform_spikes (IEEE fp32, like XLA).
// ---------------------------------------------------------------------------
__device__ __forceinline__ int in_spike(float xv, int cycle) {
    if (cycle >= T_SIM) return 0;
    float n_spk = rintf(xv * 16.0f);
    if (n_spk == 16.0f) return 1;
    if (n_spk == 0.0f)  return 0;
    float spacing = 16.0f / n_spk;
    float cf = (float)cycle;
    float q = floorf(cf / spacing);
    float r = fmodf(cf, spacing);
    return (q < n_spk && floorf(r) == 0.0f) ? 1 : 0;
}

// Build packed core-0 A matrix: row m = b*20 + t, A0[m][n] = in_spike(x[b][n], t).
__global__ __launch_bounds__(256) void gen_in_all(const float* __restrict__ x,
                                                  signed char* __restrict__ a0) {
    int gid = blockIdx.x * 256 + threadIdx.x;      // 0 .. 655359
    int e   = gid << 2;                            // logical m*2048 + n byte idx
    int row = e >> 11;                             // m = b*20 + t
    int b = row / 20, t = row - b * 20;
    int n0 = e & 2047;
    const float4 xv = *(const float4*)(x + (size_t)b * N_DIM + n0);
    uint32_t s = (uint32_t)in_spike(xv.x, t)
               | ((uint32_t)in_spike(xv.y, t) << 8)
               | ((uint32_t)in_spike(xv.z, t) << 16)
               | ((uint32_t)in_spike(xv.w, t) << 24);
    *(uint32_t*)(a0 + apk_off(row, n0)) = s;       // 4 consecutive bytes, aligned
}

// ---------------------------------------------------------------------------
// Fused batched-GEMM + threshold-scan for one core.
// Grid 512 WGs = 4 m-quarters x 128 n-strips. 256 threads = 4 waves; wave owns
// 5 m-tiles. 2-phase pipelined k-loop: stage slice ks+1 (A 20KB + B 4KB via
// global_load_lds 16B) before computing slice ks; one barrier per kstep.
// Epilogue: combined fp64 increments -> LDS transpose (reusing staging) ->
// per-(b,n) 20-step threshold scan -> packed spikes for next core / output.
// WG (q,s) owns rows [320q,320q+320) = b in [16q,16q+16) x all 20 t. 
// ---------------------------------------------------------------------------
__global__ __launch_bounds__(256, 2) void gemm_core(
        const signed char* __restrict__ wq, const signed char* __restrict__ apk,
        const float* __restrict__ biases, const float* __restrict__ thresholds,
        signed char* __restrict__ a_next, float* __restrict__ out, int c)
{
    __shared__ __align__(16) signed char smem[49152];      // 2x24KB staging
    signed char (*lds)[24 * 1024] = (signed char (*)[24 * 1024])smem;
    double* scr = (double*)smem;                            // scan scratch overlay
                                                            // [320][17] = 43520B
    const int wg  = blockIdx.x;
    const int q   = wg >> 7;           // m-quarter (20 m-tiles = 16 b's)
    const int s   = wg & 127;          // n-strip (16 cols)
    const int tid = threadIdx.x;
    const int wv  = tid >> 6;          // 0..3
    const int l   = tid & 63;

    const signed char* bsrc = wq + ((size_t)(c * 128 + s) * 32) * 4096;
    const signed char* asrc = apk + ((size_t)(q * 20) * 32) * 1024;

    auto STAGE = [&](int buf, int ks) {
#pragma unroll
        for (int r = 0; r < 5; ++r) {
            int lt = r * 4 + wv;
            __builtin_amdgcn_global_load_lds(
                (const __attribute__((address_space(1))) uint32_t*)
                    (asrc + ((size_t)lt * 32 + ks) * 1024 + l * 16),
                (__attribute__((address_space(3))) uint32_t*)(&lds[buf][lt * 1024]),
                16, 0, 0);
        }
        __builtin_amdgcn_global_load_lds(
            (const __attribute__((address_space(1))) uint32_t*)
                (bsrc + (size_t)ks * 4096 + wv * 1024 + l * 16),
            (__attribute__((address_space(3))) uint32_t*)(&lds[buf][20 * 1024 + wv * 1024]),
            16, 0, 0);
    };

    i32x4 acc[5][4];
#pragma unroll
    for (int j = 0; j < 5; ++j)
#pragma unroll
        for (int p = 0; p < 4; ++p) acc[j][p] = i32x4{0, 0, 0, 0};

    STAGE(0, 0);
    __syncthreads();
    int cur = 0;

    for (int ks = 0; ks < 32; ++ks) {
        if (ks < 31) STAGE(cur ^ 1, ks + 1);
        const signed char* lb = &lds[cur][(size_t)l * 16];
        i32x4 bf0 = *(const i32x4*)(lb + 20 * 1024);
        i32x4 bf1 = *(const i32x4*)(lb + 21 * 1024);
        i32x4 bf2 = *(const i32x4*)(lb + 22 * 1024);
        i32x4 bf3 = *(const i32x4*)(lb + 23 * 1024);
#pragma unroll
        for (int j = 0; j < 5; ++j) {
            i32x4 af = *(const i32x4*)(lb + (wv * 5 + j) * 1024);
            acc[j][0] = __builtin_amdgcn_mfma_i32_16x16x64_i8(af, bf0, acc[j][0], 0, 0, 0);
            acc[j][1] = __builtin_amdgcn_mfma_i32_16x16x64_i8(af, bf1, acc[j][1], 0, 0, 0);
            acc[j][2] = __builtin_amdgcn_mfma_i32_16x16x64_i8(af, bf2, acc[j][2], 0, 0, 0);
            acc[j][3] = __builtin_amdgcn_mfma_i32_16x16x64_i8(af, bf3, acc[j][3], 0, 0, 0);
        }
        __syncthreads();
        cur ^= 1;
    }

    // ---- Fused epilogue ----
    // 1. Combine planes exactly -> fp64 increments into LDS (staging is dead).
    const int nl = l & 15;
#pragma unroll
    for (int j = 0; j < 5; ++j) {
#pragma unroll
        for (int r = 0; r < 4; ++r) {
            int rl = (wv * 5 + j) * 16 + ((l >> 4) << 2) + r;   // local row 0..319
            long long comb = ((long long)acc[j][3][r] << 24) + ((long long)acc[j][2][r] << 16)
                           + ((long long)acc[j][1][r] << 8)  +  (long long)acc[j][0][r];
            scr[rl * 17 + nl] = (double)comb * (1.0 / 8589934592.0);
        }
    }
    __syncthreads();

    // 2. Per-(b,n) threshold scan over t=0..19; thread <-> (b_loc, n_loc).
    const int b_loc = tid >> 4;
    const int n_loc = tid & 15;
    const int b = q * 16 + b_loc;
    const int n = (s << 4) + n_loc;
    const double bv = (double)biases[c * N_DIM + n];
    const double th = (double)thresholds[c];
    double m = 0.0;
    float cnt = 0.0f;
    if (c < 3) a_next[apk_off(b * 20, n)] = 0;              // zero input at t=0
    for (int t = 0; t < CYCLES; ++t) {
        m = m + scr[(b_loc * 20 + t) * 17 + n_loc] + bv;
        bool sp = (th < m);
        if (sp) m -= th;
        if (c < 3) {
            if (t + 1 < CYCLES) a_next[apk_off(b * 20 + t + 1, n)] = sp ? 1 : 0;
        } else if (sp) {
            cnt += 1.0f;
        }
    }
    if (c == 3) out[(size_t)b * N_DIM + n] = cnt * 0.0625f; // /16, exact
}

extern "C" void kernel_launch(void* const* d_in, const int* in_sizes, int n_in,
                              void* d_out, int out_size, void* d_ws, size_t ws_size,
                              hipStream_t stream) {
    const float* x       = (const float*)d_in[0];
    const float* wts     = (const float*)d_in[1];
    const float* biases  = (const float*)d_in[2];
    const float* thr     = (const float*)d_in[3];
    float* out           = (float*)d_out;

    signed char* wq  = (signed char*)d_ws;
    signed char* sig = (signed char*)((char*)d_ws + SIG_OFF);

    // No memsets: A0 fully written by gen_in_all; A1..A3 rows fully written by
    // the previous core's fused epilogue (incl. zeroed t=0 rows); out fully
    // written by core 3's epilogue.
    pack_w<<<dim3(C_DIM * 32 * 128), dim3(64), 0, stream>>>(wts, wq);
    gen_in_all<<<dim3(M_ROWS * N_DIM / 4 / 256), dim3(256), 0, stream>>>(x, sig);

    for (int c = 0; c < C_DIM; ++c) {
        const signed char* a_cur = sig + (size_t)c * AMAT_BYTES;
        signed char* a_nxt = (c < 3) ? (signed char*)(sig + (size_t)(c + 1) * AMAT_BYTES)
                                     : (signed char*)sig;   // unused for c==3
        gemm_core<<<dim3(512), dim3(256), 0, stream>>>(wq, a_cur, biases, thr,
                                                       a_nxt, out, c);
    }
}

// Round 6
// 107.386 us; speedup vs baseline: 4.2957x; 1.3146x over previous
//
#include <hip/hip_runtime.h>
#include <cstdint>
#include <cstddef>

// SpikingHybridCoreFlow: 20-cycle spiking simulation.
// Exactness strategy (unchanged): fixed-point weights (4 x i8 planes, scale
// 2^-33), i8 MFMA integer GEMM (order-independent exact), fp64 membrane.
//
// R6: (a) gemm WGs widened to 32 output cols (8 m-eighths x 64 strips):
// A-operand L2 traffic halved, per-kstep stage bytes 24->18KB => loop is
// MFMA-bound (floor ~11us/core). (b) W packing for core c+1 fused into
// gemm_core(c) as extra blocks (memory-bound pack overlaps MFMA-bound gemm);
// only W0 pack + input-spike gen remain up front in one prep0 launch.

#define N_DIM 2048
#define B_DIM 64
#define C_DIM 4
#define T_SIM 16
#define CYCLES 20
#define M_ROWS (CYCLES * B_DIM)          // 1280

using i32x4 = __attribute__((ext_vector_type(4))) int;
using u32x4 = __attribute__((ext_vector_type(4))) uint32_t;

// Workspace layout
//   WQ  : [C][128 strips][32 ksteps][4 planes][1024B] = 67,108,864 B
//   SIG : 4 x packed A matrices [80 mt][32 ks][1024B]  = 10,485,760 B
static constexpr size_t WQ_CORE    = (size_t)128 * 32 * 4 * 1024;   // 16 MB
static constexpr size_t SIG_OFF    = (size_t)C_DIM * WQ_CORE;
static constexpr size_t AMAT_BYTES = (size_t)M_ROWS * N_DIM;

// Packed-A byte offset for logical (m, k); m = b*20 + t.
//   block = (m>>4)*32 + (k>>6); in-block = ((k>>4)&3)*256 + (m&15)*16 + (k&15)
// = the i8 16x16x64 A-fragment order (lane*16 + j).
__device__ __forceinline__ size_t apk_off(int m, int k) {
    return ((size_t)((m >> 4) * 32 + (k >> 6)) << 10)
         + (size_t)((((k >> 4) & 3) << 8) + ((m & 15) << 4) + (k & 15));
}

// ---------------------------------------------------------------------------
// Pack one (ct,ks) block of one core's W: fp32 -> i32 fixed point (scale 2^33)
// -> 4 balanced i8 planes, MFMA B-fragment order, coalesced dwordx4 stores.
// unit = ks*128 + ct? No: unit & 127 = ct, unit >> 7 = ks. l = lane 0..63.
// ---------------------------------------------------------------------------
__device__ __forceinline__ void pack_unit(const float* __restrict__ wc,
                                          signed char* __restrict__ wqc,
                                          int unit, int l) {
    int ct = unit & 127;
    int ks = unit >> 7;                // 0..31
    int n     = ct * 16 + (l & 15);
    int abase = ks * 64 + ((l >> 4) << 4);
    size_t blk_base = (((size_t)ct * 32 + ks) * 4) * 1024 + (size_t)l * 16;

    u32x4 d0, d1, d2, d3;
    for (int j4 = 0; j4 < 4; ++j4) {
        uint32_t w0 = 0, w1 = 0, w2 = 0, w3 = 0;
        for (int i = 0; i < 4; ++i) {
            int a = abase + j4 * 4 + i;
            float wv = wc[(size_t)a * N_DIM + n];
            long long vi = llrintf(wv * 8589934592.0f);        // * 2^33, exact
            int v  = (int)vi;
            int b0 = (int)(signed char)(v & 255); v = (v - b0) >> 8;
            int b1 = (int)(signed char)(v & 255); v = (v - b1) >> 8;
            int b2 = (int)(signed char)(v & 255); v = (v - b2) >> 8;
            int b3 = v;
            w0 |= (uint32_t)(uint8_t)b0 << (8 * i);
            w1 |= (uint32_t)(uint8_t)b1 << (8 * i);
            w2 |= (uint32_t)(uint8_t)b2 << (8 * i);
            w3 |= (uint32_t)(uint8_t)b3 << (8 * i);
        }
        d0[j4] = w0; d1[j4] = w1; d2[j4] = w2; d3[j4] = w3;
    }
    *(u32x4*)(wqc + blk_base)        = d0;
    *(u32x4*)(wqc + blk_base + 1024) = d1;
    *(u32x4*)(wqc + blk_base + 2048) = d2;
    *(u32x4*)(wqc + blk_base + 3072) = d3;
}

// ---------------------------------------------------------------------------
// Bit-exact replication of _uniform_spikes (IEEE fp32, like XLA).
// ---------------------------------------------------------------------------
__device__ __forceinline__ int in_spike(float xv, int cycle) {
    if (cycle >= T_SIM) return 0;
    float n_spk = rintf(xv * 16.0f);
    if (n_spk == 16.0f) return 1;
    if (n_spk == 0.0f)  return 0;
    float spacing = 16.0f / n_spk;
    float cf = (float)cycle;
    float q = floorf(cf / spacing);
    float r = fmodf(cf, spacing);
    return (q < n_spk && floorf(r) == 0.0f) ? 1 : 0;
}

// Packed core-0 A element group: row m = b*20 + t, 4 n's per thread.
__device__ __forceinline__ void gen_unit(const float* __restrict__ x,
                                         signed char* __restrict__ a0, int gid) {
    int e   = gid << 2;                            // logical m*2048 + n byte idx
    int row = e >> 11;                             // m = b*20 + t
    int b = row / 20, t = row - b * 20;
    int n0 = e & 2047;
    const float4 xv = *(const float4*)(x + (size_t)b * N_DIM + n0);
    uint32_t s = (uint32_t)in_spike(xv.x, t)
               | ((uint32_t)in_spike(xv.y, t) << 8)
               | ((uint32_t)in_spike(xv.z, t) << 16)
               | ((uint32_t)in_spike(xv.w, t) << 24);
    *(uint32_t*)(a0 + apk_off(row, n0)) = s;
}

// prep0: blocks [0,1024) pack core-0 W (4 units each); [1024,3584) gen input.
__global__ __launch_bounds__(256) void prep0(const float* __restrict__ w,
                                             signed char* __restrict__ wq,
                                             const float* __restrict__ x,
                                             signed char* __restrict__ a0) {
    int wg = blockIdx.x, tid = threadIdx.x;
    if (wg < 1024) {
        pack_unit(w, wq, (wg << 2) | (tid >> 6), tid & 63);
    } else {
        gen_unit(x, a0, (wg - 1024) * 256 + tid);
    }
}

// ---------------------------------------------------------------------------
// Fused batched-GEMM + threshold-scan for one core, + overlapped W_{c+1} pack.
// Gemm WGs (wg<512): 8 m-eighths (8 b's = 160 rows = 10 m-tiles) x 64 strips
// (32 cols). 256 thr = 4 waves; wave wv: nc = wv&1, m-tiles (wv>>1)*5+0..4
// -> acc[5][4] (80 VGPR). Per kstep stage 18KB (10 A + 8 B blocks) into
// lds[buf^1] before computing lds[buf]; one __syncthreads per kstep.
// Epilogue: exact plane combine -> fp64 scr[160][33] -> per-(b,n) 20-step
// threshold scan -> packed spikes for next core / output.
// Pack WGs (wg>=512, c<3): pack W_{c+1} (memory-bound, overlaps gemm).
// ---------------------------------------------------------------------------
__global__ __launch_bounds__(256, 2) void gemm_core(
        signed char* __restrict__ wq, const signed char* __restrict__ apk,
        const float* __restrict__ wts, const float* __restrict__ biases,
        const float* __restrict__ thresholds,
        signed char* __restrict__ a_next, float* __restrict__ out, int c)
{
    __shared__ __align__(16) signed char smem[42240];   // 2x18KB stage / scr
    const int wg  = blockIdx.x;
    const int tid = threadIdx.x;
    const int wv  = tid >> 6;          // 0..3
    const int l   = tid & 63;

    if (wg >= 512) {                   // overlapped pack of W_{c+1}
        pack_unit(wts + (size_t)(c + 1) * N_DIM * N_DIM,
                  wq + (size_t)(c + 1) * WQ_CORE,
                  ((wg - 512) << 2) | wv, l);
        return;
    }

    const int e8 = wg >> 6;            // m-eighth: b in [8*e8, 8*e8+8)
    const int s  = wg & 63;            // 32-col strip: n in [32s, 32s+32)

    const signed char* asrc  = apk + ((size_t)(e8 * 10) * 32) * 1024;
    const signed char* b0src = wq + ((size_t)(c * 128 + s * 2) * 32) * 4096;
    const signed char* b1src = wq + ((size_t)(c * 128 + s * 2 + 1) * 32) * 4096;

    // Stage slice ks into buffer buf. Waves 0,1: A blocks (5 each);
    // waves 2,3: B strip0/strip1 (4 plane-blocks each). 1KB per DMA load.
    auto STAGE = [&](int buf, int ks) {
        signed char* dst = smem + buf * 18432;
        if (wv < 2) {
#pragma unroll
            for (int r = 0; r < 5; ++r) {
                int blk = wv * 5 + r;
                __builtin_amdgcn_global_load_lds(
                    (const __attribute__((address_space(1))) uint32_t*)
                        (asrc + ((size_t)blk * 32 + ks) * 1024 + l * 16),
                    (__attribute__((address_space(3))) uint32_t*)(dst + blk * 1024),
                    16, 0, 0);
            }
        } else {
            const signed char* bs = (wv == 2) ? b0src : b1src;
#pragma unroll
            for (int p = 0; p < 4; ++p) {
                __builtin_amdgcn_global_load_lds(
                    (const __attribute__((address_space(1))) uint32_t*)
                        (bs + (size_t)ks * 4096 + p * 1024 + l * 16),
                    (__attribute__((address_space(3))) uint32_t*)
                        (dst + 10240 + (wv - 2) * 4096 + p * 1024),
                    16, 0, 0);
            }
        }
    };

    const int nc  = wv & 1;            // n-fragment (16 cols)
    const int mtb = (wv >> 1) * 5;     // first of 5 m-tiles

    i32x4 acc[5][4];
#pragma unroll
    for (int j = 0; j < 5; ++j)
#pragma unroll
        for (int p = 0; p < 4; ++p) acc[j][p] = i32x4{0, 0, 0, 0};

    STAGE(0, 0);
    __syncthreads();
    int cur = 0;

    for (int ks = 0; ks < 32; ++ks) {
        if (ks < 31) STAGE(cur ^ 1, ks + 1);
        const signed char* lb = smem + cur * 18432 + (size_t)l * 16;
        i32x4 bf0 = *(const i32x4*)(lb + 10240 + nc * 4096);
        i32x4 bf1 = *(const i32x4*)(lb + 10240 + nc * 4096 + 1024);
        i32x4 bf2 = *(const i32x4*)(lb + 10240 + nc * 4096 + 2048);
        i32x4 bf3 = *(const i32x4*)(lb + 10240 + nc * 4096 + 3072);
#pragma unroll
        for (int j = 0; j < 5; ++j) {
            i32x4 af = *(const i32x4*)(lb + (mtb + j) * 1024);
            acc[j][0] = __builtin_amdgcn_mfma_i32_16x16x64_i8(af, bf0, acc[j][0], 0, 0, 0);
            acc[j][1] = __builtin_amdgcn_mfma_i32_16x16x64_i8(af, bf1, acc[j][1], 0, 0, 0);
            acc[j][2] = __builtin_amdgcn_mfma_i32_16x16x64_i8(af, bf2, acc[j][2], 0, 0, 0);
            acc[j][3] = __builtin_amdgcn_mfma_i32_16x16x64_i8(af, bf3, acc[j][3], 0, 0, 0);
        }
        __syncthreads();
        cur ^= 1;
    }

    // ---- Fused epilogue ----
    // 1. Combine planes exactly -> fp64 increments into LDS (staging is dead).
    double* scr = (double*)smem;                   // [160][33]
    const int nl = nc * 16 + (l & 15);
#pragma unroll
    for (int j = 0; j < 5; ++j) {
#pragma unroll
        for (int r = 0; r < 4; ++r) {
            int rl = (mtb + j) * 16 + ((l >> 4) << 2) + r;   // local row 0..159
            long long comb = ((long long)acc[j][3][r] << 24) + ((long long)acc[j][2][r] << 16)
                           + ((long long)acc[j][1][r] << 8)  +  (long long)acc[j][0][r];
            scr[rl * 33 + nl] = (double)comb * (1.0 / 8589934592.0);
        }
    }
    __syncthreads();

    // 2. Per-(b,n) threshold scan over t=0..19; thread <-> (b_loc, n_loc).
    const int b_loc = tid >> 5;        // 0..7
    const int n_loc = tid & 31;        // 0..31
    const int b = e8 * 8 + b_loc;
    const int n = (s << 5) + n_loc;
    const double bv = (double)biases[c * N_DIM + n];
    const double th = (double)thresholds[c];
    double m = 0.0;
    float cnt = 0.0f;
    if (c < 3) a_next[apk_off(b * 20, n)] = 0;     // zero input at t=0
    for (int t = 0; t < CYCLES; ++t) {
        m = m + scr[(b_loc * 20 + t) * 33 + n_loc] + bv;
        bool sp = (th < m);
        if (sp) m -= th;
        if (c < 3) {
            if (t + 1 < CYCLES) a_next[apk_off(b * 20 + t + 1, n)] = sp ? 1 : 0;
        } else if (sp) {
            cnt += 1.0f;
        }
    }
    if (c == 3) out[(size_t)b * N_DIM + n] = cnt * 0.0625f;  // /16, exact
}

extern "C" void kernel_launch(void* const* d_in, const int* in_sizes, int n_in,
                              void* d_out, int out_size, void* d_ws, size_t ws_size,
                              hipStream_t stream) {
    const float* x       = (const float*)d_in[0];
    const float* wts     = (const float*)d_in[1];
    const float* biases  = (const float*)d_in[2];
    const float* thr     = (const float*)d_in[3];
    float* out           = (float*)d_out;

    signed char* wq  = (signed char*)d_ws;
    signed char* sig = (signed char*)((char*)d_ws + SIG_OFF);

    // prep0: pack W0 + build packed core-0 input spikes (no memsets needed:
    // every consumed byte is written by a producer before its consumer runs).
    prep0<<<dim3(3584), dim3(256), 0, stream>>>(wts, wq, x, sig);

    // 4 pipeline stages: fused GEMM+scan, with W_{c+1} pack overlapped.
    for (int c = 0; c < C_DIM; ++c) {
        const signed char* a_cur = sig + (size_t)c * AMAT_BYTES;
        signed char* a_nxt = (c < 3) ? (signed char*)(sig + (size_t)(c + 1) * AMAT_BYTES)
                                     : (signed char*)sig;   // unused for c==3
        int grid = (c < 3) ? 1536 : 512;
        gemm_core<<<dim3(grid), dim3(256), 0, stream>>>(wq, a_cur, wts, biases,
                                                        thr, a_nxt, out, c);
    }
}